// Round 9
// baseline (235.949 us; speedup 1.0000x reference)
//
#include <hip/hip_runtime.h>

// Sparse conv block, output-major, 64-bit packed exch-chain (round 9):
//   build: per pair atomicExch of packed {in,id} head + coalesced node write;
//          non-first inserters atomicOr a multi-flag (bit63) onto the head
//   compact: PURE COALESCED pass: head -> ginx (ZROW / in / aux slot)
//   fixup: aux rows (cnt>=2) = bf16 sum of chain rows (walk via node)
//   conv: round-6 proven shape: 128 rows/block, single gather + 16 MFMA per
//         k per wave, W[k] LDS dbuf + XOR-swizzle, fused BN stats
//   norm: BN+ReLU.                                MI355X / gfx950.

#define N_VOX   100000
#define NPAD    100096                  // multiple of 64
#define K3      27
#define M_PAIRS 40000
#define NPAIRS  (K3 * M_PAIRS)          // 1,080,000
#define BN_EPS  1e-5f
#define NBINS   (K3 * NPAD)             // 2,702,592
#define AUXMAX  184320                  // E[cnt>=2 bins] = 166.2k, ~44 sigma headroom
#define AUXCAP  (AUXMAX - 1)
#define ZROW    (N_VOX + AUXMAX - 1)    // zeroed gather row (empty bins)
#define SENT    0xFFFFFFFFFFFFFFFFull
#define MFLAG   (1ull << 63)

// ---- workspace layout (bytes), total 57,539,648 (< proven-fit 64,903,232) ---
#define OFF_WT     0u                       // bf16 Wt[k][c][i]        221,184
#define OFF_STATS  221184u                  // f32[128]
#define OFF_CTRS   221696u                  // [0]=aux counter
#define OFF_GINX   221760u                  // int ginx[NBINS]      10,810,368
#define OFF_NODE   11032128u                // u64 node[NPAIRS]      8,640,000
#define OFF_LIST   19672128u                // u64 list[AUXMAX]      1,474,560
#define OFF_XB     21146688u                // bf16 rows[N_VOX+AUXMAX][64] 36,392,960
// bh aliased into xb's AUX region (dead after compact; fixup/ZROW don't clash:
// bh spans aux rows [0,168913); ZROW is aux row 184319; fixup writes only
// allocated slots AFTER compact has consumed bh)
#define OFF_BH     (OFF_XB + 12800000u)     // u64 bh[NBINS]        21,620,736
#define WS_NEED    ((size_t)OFF_XB + (size_t)(N_VOX + AUXMAX) * 128u)

#define NB_WT    432                    // 27*4096/256
#define NB_XB    3125                   // ceil(N_VOX*8/256)
#define NB_BUILD 4219                   // ceil(NPAIRS/256)
#define GRID_IB  (NB_WT + NB_XB + 1 + NB_BUILD)   // 7777

typedef __attribute__((ext_vector_type(8))) short bf16x8;
typedef __attribute__((ext_vector_type(4))) float f32x4;
typedef unsigned long long u64;

__device__ __forceinline__ short f2bf(float f) {
  unsigned u = __builtin_bit_cast(unsigned, f);
  u += 0x7FFFu + ((u >> 16) & 1u);
  return (short)(u >> 16);
}
__device__ __forceinline__ float bf2f(short s) {
  unsigned u = ((unsigned)(unsigned short)s) << 16;
  return __builtin_bit_cast(float, u);
}

// ---- fused init + build -----------------------------------------------------
// blocks [0,NB_WT): W relayout; [NB_WT,+NB_XB): x->bf16; one block: ZROW;
// rest: packed exch-chain insert.
__global__ __launch_bounds__(256) void init_build_kernel(const float* __restrict__ W,
                                                         const float* __restrict__ x,
                                                         const int* __restrict__ in_idx,
                                                         const int* __restrict__ out_idx,
                                                         short* __restrict__ wt,
                                                         short* __restrict__ xb,
                                                         u64* __restrict__ bh,
                                                         u64* __restrict__ node) {
  int b = blockIdx.x, t = threadIdx.x;
  if (b < NB_WT) {
    int id = b * 256 + t;
    int k = id >> 12, rem = id & 4095, c = rem >> 6, i = rem & 63;
    wt[id] = f2bf(W[(k << 12) + (i << 6) + c]);     // wt[k][c][i]
  } else if (b < NB_WT + NB_XB) {
    int id = (b - NB_WT) * 256 + t;
    if (id < N_VOX * 8) {
      float4 lo = ((const float4*)x)[id * 2];
      float4 hi = ((const float4*)x)[id * 2 + 1];
      bf16x8 v;
      v[0] = f2bf(lo.x); v[1] = f2bf(lo.y); v[2] = f2bf(lo.z); v[3] = f2bf(lo.w);
      v[4] = f2bf(hi.x); v[5] = f2bf(hi.y); v[6] = f2bf(hi.z); v[7] = f2bf(hi.w);
      ((bf16x8*)xb)[id] = v;
    }
  } else if (b == NB_WT + NB_XB) {
    if (t < 8) {
      bf16x8 z = {0, 0, 0, 0, 0, 0, 0, 0};
      ((bf16x8*)(xb + (size_t)ZROW * 64))[t] = z;
    }
  } else {
    int id = (b - (NB_WT + NB_XB + 1)) * 256 + t;
    if (id < NPAIRS) {
      int k  = id / M_PAIRS;
      int in = in_idx[id];
      int o  = out_idx[id];
      int bb = k * NPAD + o;
      u64 nh  = ((u64)(unsigned)in << 32) | (unsigned)id;
      u64 old = atomicExch(&bh[bb], nh);
      node[id] = old;
      // any non-first inserter flags the bin multi; the LAST exch-er always
      // sees old!=SENT and its OR lands after its own exch -> flag sticks.
      if (old != SENT) atomicOr(&bh[bb], MFLAG);
    }
  }
}

// ---- compact: pure coalesced head -> ginx; multi -> aux slot ----------------
__global__ __launch_bounds__(256) void compact_kernel(const u64* __restrict__ bh,
                                                      int* __restrict__ ginx,
                                                      u64* __restrict__ list,
                                                      int* __restrict__ ctrs) {
  __shared__ int l_cnt, l_base;
  int t = threadIdx.x;
  if (t == 0) l_cnt = 0;
  __syncthreads();
  int w = blockIdx.x * 256 + t;                 // 4 bins per thread
  bool ok = (w < NBINS / 4);
  u64 h[4];
  if (ok) {
    ulonglong2 p0 = ((const ulonglong2*)bh)[w * 2];
    ulonglong2 p1 = ((const ulonglong2*)bh)[w * 2 + 1];
    h[0] = p0.x; h[1] = p0.y; h[2] = p1.x; h[3] = p1.y;
  } else {
    h[0] = SENT; h[1] = SENT; h[2] = SENT; h[3] = SENT;
  }
  int gv[4], lp[4];
  #pragma unroll
  for (int s = 0; s < 4; ++s) {
    lp[s] = -1;
    if (h[s] == SENT)            gv[s] = ZROW;
    else if (!(h[s] >> 63))      gv[s] = (int)((h[s] >> 32) & 0x7FFFFFFFu);
    else                         lp[s] = atomicAdd(&l_cnt, 1);
  }
  __syncthreads();
  if (t == 0) l_base = (l_cnt > 0) ? atomicAdd(&ctrs[0], l_cnt) : 0;
  __syncthreads();
  #pragma unroll
  for (int s = 0; s < 4; ++s) {
    if (lp[s] >= 0) {
      int pos = l_base + lp[s];
      if (pos < AUXCAP) { list[pos] = h[s]; gv[s] = N_VOX + pos; }
      else              { gv[s] = (int)((h[s] >> 32) & 0x7FFFFFFFu); }  // guard
    }
  }
  if (ok) ((int4*)ginx)[w] = make_int4(gv[0], gv[1], gv[2], gv[3]);
}

// ---- fixup: aux row = f32 sum of chain's input rows (bf16 out) --------------
__global__ __launch_bounds__(256) void fixup_kernel(short* __restrict__ xb,
                                                    const u64* __restrict__ list,
                                                    const u64* __restrict__ node,
                                                    const int* __restrict__ ctrs) {
  int n = ctrs[0]; if (n > AUXCAP) n = AUXCAP;
  int wid  = (blockIdx.x * 256 + threadIdx.x) >> 6;
  int lane = threadIdx.x & 63;
  int nw   = gridDim.x * 4;
  for (int i = wid; i < n; i += nw) {
    u64 h = list[i];
    int in0     = (int)((h >> 32) & 0x7FFFFFFFu);
    unsigned id = (unsigned)(h & 0xFFFFFFFFu);
    float acc = bf2f(xb[(size_t)in0 * 64 + lane]);
    u64 v = node[id];                           // wave-uniform broadcast
    while (v != SENT) {
      int in = (int)((v >> 32) & 0x7FFFFFFFu);
      id = (unsigned)(v & 0xFFFFFFFFu);
      acc += bf2f(xb[(size_t)in * 64 + lane]);
      v = node[id];
    }
    xb[(size_t)(N_VOX + i) * 64 + lane] = f2bf(acc);
  }
}

// ---- conv: round-6 proven shape: 128 rows/block (32/wave); per k per wave:
//      1 gather set + 16 MFMA; W[k] LDS dbuf + XOR-swizzle; depth-1 row
//      prefetch + depth-2 idx; fused BN stats; NO launch-bounds cap ----------
// A lane l: row=l&15, k-slots (l>>4)*8+j (+32);  B lane l: col=l&15, same slots.
// C/D: col=lane&15, row=(lane>>4)*4+reg  [rounds 1-8 proven].
// LDS swizzle: logical byte ^= ((row c)&7)<<4   [rounds 5-8 proven].
__global__ __launch_bounds__(256) void conv_out_kernel(const short* __restrict__ xb,
                                                       const short* __restrict__ wt,
                                                       const int* __restrict__ ginx,
                                                       float* __restrict__ out,
                                                       float* __restrict__ stats) {
  __shared__ short lds[2 * 4096];               // 2 x 8 KB W double buffer
  __shared__ float ls[128];
  int t = threadIdx.x, wave = t >> 6, lane = t & 63;
  int g = lane >> 4, c0 = lane & 15, g8 = g * 8;
  int o0 = blockIdx.x * 128 + wave * 32 + c0;   // rows 0..15 of this wave
  int o1 = o0 + 16;                             // rows 16..31

  int rb  = ((c0 * 128 + g * 16) ^ ((c0 & 7) << 4)) >> 1;
  int wb0 = ((t * 32) ^ (((t >> 2) & 7) << 4)) >> 1;
  if (t < 128) ls[t] = 0.f;

  f32x4 acc0[4], acc1[4];
  #pragma unroll
  for (int n = 0; n < 4; ++n) {
    acc0[n][0]=0.f; acc0[n][1]=0.f; acc0[n][2]=0.f; acc0[n][3]=0.f;
    acc1[n][0]=0.f; acc1[n][1]=0.f; acc1[n][2]=0.f; acc1[n][3]=0.f;
  }

  // prologue: stage W0, gather k=0 rows, idx k=1
  bf16x8 s0w = *(const bf16x8*)(wt + t * 16);
  bf16x8 s1w = *(const bf16x8*)(wt + t * 16 + 8);
  int ia = ginx[o0], ib = ginx[o1];
  const short* xa = xb + (size_t)ia * 64;
  const short* xc = xb + (size_t)ib * 64;
  bf16x8 a0c = *(const bf16x8*)(xa + g8);
  bf16x8 a1c = *(const bf16x8*)(xa + 32 + g8);
  bf16x8 a2c = *(const bf16x8*)(xc + g8);
  bf16x8 a3c = *(const bf16x8*)(xc + 32 + g8);
  int i1a = ginx[NPAD + o0], i1b = ginx[NPAD + o1];
  *(bf16x8*)&lds[wb0]     = s0w;
  *(bf16x8*)&lds[wb0 ^ 8] = s1w;
  __syncthreads();

  int buf = 0;
  for (int k = 0; k < K3; ++k) {
    if (k + 1 < K3) {                           // W stage loads for k+1
      const short* wn = wt + (size_t)(k + 1) * 4096 + t * 16;
      s0w = *(const bf16x8*)(wn);
      s1w = *(const bf16x8*)(wn + 8);
    }
    // gather rows for k+1 (branchless: empty -> ZROW, L1-hot)
    const short* pa = xb + (size_t)i1a * 64;
    const short* pb = xb + (size_t)i1b * 64;
    bf16x8 a0n = *(const bf16x8*)(pa + g8);
    bf16x8 a1n = *(const bf16x8*)(pa + 32 + g8);
    bf16x8 a2n = *(const bf16x8*)(pb + g8);
    bf16x8 a3n = *(const bf16x8*)(pb + 32 + g8);
    int i2a = ZROW, i2b = ZROW;
    if (k + 2 < K3) {
      i2a = ginx[(size_t)(k + 2) * NPAD + o0];
      i2b = ginx[(size_t)(k + 2) * NPAD + o1];
    }
    // compute k from lds[buf]
    const short* lb = lds + buf * 4096;
    #pragma unroll
    for (int n = 0; n < 4; ++n) {
      bf16x8 b0 = *(const bf16x8*)&lb[rb + n * 1024];
      bf16x8 b1 = *(const bf16x8*)&lb[(rb ^ 32) + n * 1024];
      acc0[n] = __builtin_amdgcn_mfma_f32_16x16x32_bf16(a0c, b0, acc0[n], 0, 0, 0);
      acc0[n] = __builtin_amdgcn_mfma_f32_16x16x32_bf16(a1c, b1, acc0[n], 0, 0, 0);
      acc1[n] = __builtin_amdgcn_mfma_f32_16x16x32_bf16(a2c, b0, acc1[n], 0, 0, 0);
      acc1[n] = __builtin_amdgcn_mfma_f32_16x16x32_bf16(a3c, b1, acc1[n], 0, 0, 0);
    }
    if (k + 1 < K3) {                           // publish W k+1
      short* wd = lds + (buf ^ 1) * 4096;
      *(bf16x8*)&wd[wb0]     = s0w;
      *(bf16x8*)&wd[wb0 ^ 8] = s1w;
    }
    __syncthreads();
    a0c = a0n; a1c = a1n; a2c = a2n; a3c = a3n;
    i1a = i2a; i1b = i2b; buf ^= 1;
  }

  // store: each out row exactly once
  int orow = blockIdx.x * 128 + wave * 32 + (g << 2);
  #pragma unroll
  for (int j = 0; j < 4; ++j) {
    int r0 = orow + j, r1 = orow + 16 + j;
    if (r0 < N_VOX) {
      float* op = out + (size_t)r0 * 64 + c0;
      op[0] = acc0[0][j]; op[16] = acc0[1][j]; op[32] = acc0[2][j]; op[48] = acc0[3][j];
    }
    if (r1 < N_VOX) {
      float* op = out + (size_t)r1 * 64 + c0;
      op[0] = acc1[0][j]; op[16] = acc1[1][j]; op[32] = acc1[2][j]; op[48] = acc1[3][j];
    }
  }

  // fused BN stats (padding rows hold exact zeros -> contribute nothing)
  #pragma unroll
  for (int n = 0; n < 4; ++n) {
    float s = 0.f, q = 0.f;
    #pragma unroll
    for (int j = 0; j < 4; ++j) {
      float v0 = acc0[n][j], v1 = acc1[n][j];
      s += v0 + v1; q += v0 * v0 + v1 * v1;
    }
    atomicAdd(&ls[n * 16 + c0], s);
    atomicAdd(&ls[64 + n * 16 + c0], q);
  }
  __syncthreads();
  if (t < 128) unsafeAtomicAdd(&stats[t], ls[t]);
}

// ---- finalize BN + ReLU in place -------------------------------------------
__global__ __launch_bounds__(256) void norm_kernel(float* __restrict__ out,
                                                   const float* __restrict__ stats,
                                                   const float* __restrict__ gamma,
                                                   const float* __restrict__ beta) {
  int i4 = blockIdx.x * 256 + threadIdx.x;
  if (i4 >= N_VOX * 16) return;
  const float invN = 1.0f / (float)N_VOX;
  float4 v = ((const float4*)out)[i4];
  int c0 = (i4 << 2) & 63;
  float r[4] = {v.x, v.y, v.z, v.w};
  #pragma unroll
  for (int j = 0; j < 4; ++j) {
    int c = c0 + j;
    float mean = stats[c] * invN;
    float ex2  = stats[64 + c] * invN;
    float var  = ex2 - mean * mean;
    float scale = gamma[c] * rsqrtf(var + BN_EPS);
    float shift = beta[c] - mean * scale;
    r[j] = fmaxf(r[j] * scale + shift, 0.0f);
  }
  v.x = r[0]; v.y = r[1]; v.z = r[2]; v.w = r[3];
  ((float4*)out)[i4] = v;
}

extern "C" void kernel_launch(void* const* d_in, const int* in_sizes, int n_in,
                              void* d_out, int out_size, void* d_ws, size_t ws_size,
                              hipStream_t stream) {
  const float* x      = (const float*)d_in[0];
  const float* W      = (const float*)d_in[1];
  const float* gamma  = (const float*)d_in[2];
  const float* beta   = (const float*)d_in[3];
  const int*   in_idx = (const int*)d_in[4];
  const int*   out_idx= (const int*)d_in[5];
  float* out = (float*)d_out;

  char* ws = (char*)d_ws;
  short* wt    = (short*)(ws + OFF_WT);
  float* stats = (float*)(ws + OFF_STATS);
  int*   ctrs  = (int*)(ws + OFF_CTRS);
  int*   ginx  = (int*)(ws + OFF_GINX);
  u64*   node  = (u64*)(ws + OFF_NODE);
  u64*   list  = (u64*)(ws + OFF_LIST);
  short* xb    = (short*)(ws + OFF_XB);
  u64*   bh    = (u64*)(ws + OFF_BH);           // aliased into xb aux region

  hipMemsetAsync(ws + OFF_STATS, 0, OFF_GINX - OFF_STATS, stream);  // stats+ctrs
  hipMemsetAsync((void*)bh, 0xFF, (size_t)NBINS * 8, stream);       // heads = SENT

  init_build_kernel<<<GRID_IB, 256, 0, stream>>>(W, x, in_idx, out_idx,
                                                 wt, xb, bh, node);
  compact_kernel<<<(NBINS / 4 + 255) / 256, 256, 0, stream>>>(bh, ginx, list, ctrs);
  fixup_kernel<<<2048, 256, 0, stream>>>(xb, list, node, ctrs);
  conv_out_kernel<<<NPAD / 128, 256, 0, stream>>>(xb, wt, ginx, out, stats);
  norm_kernel<<<(N_VOX * 16 + 255) / 256, 256, 0, stream>>>(out, stats, gamma, beta);
}

// Round 10
// 218.113 us; speedup vs baseline: 1.0818x; 1.0818x over previous
//
#include <hip/hip_runtime.h>

// Sparse conv block, output-major, 64-bit packed exch-chain (round 10):
//   init (STREAMING ONLY, de-fused from build): bf16 prep of W/x, ZROW
//   build (ATOMICS ONLY): per pair atomicExch packed {in,id} head + coalesced
//          node write; non-first inserters atomicOr multi-flag (bit63)
//   compact: pure coalesced head -> ginx (ZROW / in / aux slot)
//   fixup: aux rows (cnt>=2) = bf16 sum of chain rows (wave per bin)
//   conv: 128 rows/block, DEPTH-2 row prefetch (3 gather stages in flight,
//         fully unrolled k-loop), W[k] LDS dbuf + XOR-swizzle, fused BN stats
//   norm: BN+ReLU.                                MI355X / gfx950.

#define N_VOX   100000
#define NPAD    100096                  // multiple of 64
#define K3      27
#define M_PAIRS 40000
#define NPAIRS  (K3 * M_PAIRS)          // 1,080,000
#define BN_EPS  1e-5f
#define NBINS   (K3 * NPAD)             // 2,702,592
#define AUXMAX  184320                  // E[cnt>=2 bins] = 166.2k
#define AUXCAP  (AUXMAX - 1)
#define ZROW    (N_VOX + AUXMAX - 1)    // zeroed gather row (empty bins)
#define SENT    0xFFFFFFFFFFFFFFFFull
#define MFLAG   (1ull << 63)

// ---- workspace layout (bytes) — identical to round 9 (proven fit) ----------
#define OFF_WT     0u                       // bf16 Wt[k][c][i]        221,184
#define OFF_STATS  221184u                  // f32[128]
#define OFF_CTRS   221696u                  // [0]=aux counter
#define OFF_GINX   221760u                  // int ginx[NBINS]      10,810,368
#define OFF_NODE   11032128u                // u64 node[NPAIRS]      8,640,000
#define OFF_LIST   19672128u                // u64 list[AUXMAX]      1,474,560
#define OFF_XB     21146688u                // bf16 rows[N_VOX+AUXMAX][64]
// bh aliased into xb's AUX region (dead after compact; fixup writes only
// allocated aux slots AFTER compact; ZROW byte offset 36.39M > bh end 34.42M)
#define OFF_BH     (OFF_XB + 12800000u)     // u64 bh[NBINS]        21,620,736
#define WS_NEED    ((size_t)OFF_XB + (size_t)(N_VOX + AUXMAX) * 128u)

#define NB_WT    432                    // 27*4096/256
#define NB_XB    3125                   // ceil(N_VOX*8/256)
#define GRID_IN  (NB_WT + NB_XB + 1)    // 3558
#define NB_BUILD 4219                   // ceil(NPAIRS/256)

typedef __attribute__((ext_vector_type(8))) short bf16x8;
typedef __attribute__((ext_vector_type(4))) float f32x4;
typedef unsigned long long u64;

__device__ __forceinline__ short f2bf(float f) {
  unsigned u = __builtin_bit_cast(unsigned, f);
  u += 0x7FFFu + ((u >> 16) & 1u);
  return (short)(u >> 16);
}
__device__ __forceinline__ float bf2f(short s) {
  unsigned u = ((unsigned)(unsigned short)s) << 16;
  return __builtin_bit_cast(float, u);
}

// ---- init: PURE STREAMING (de-fused so it runs at full HBM rate) ------------
__global__ __launch_bounds__(256) void init_kernel(const float* __restrict__ W,
                                                   const float* __restrict__ x,
                                                   short* __restrict__ wt,
                                                   short* __restrict__ xb) {
  int b = blockIdx.x, t = threadIdx.x;
  if (b < NB_WT) {
    int id = b * 256 + t;
    int k = id >> 12, rem = id & 4095, c = rem >> 6, i = rem & 63;
    wt[id] = f2bf(W[(k << 12) + (i << 6) + c]);     // wt[k][c][i]
  } else if (b < NB_WT + NB_XB) {
    int id = (b - NB_WT) * 256 + t;
    if (id < N_VOX * 8) {
      float4 lo = ((const float4*)x)[id * 2];
      float4 hi = ((const float4*)x)[id * 2 + 1];
      bf16x8 v;
      v[0] = f2bf(lo.x); v[1] = f2bf(lo.y); v[2] = f2bf(lo.z); v[3] = f2bf(lo.w);
      v[4] = f2bf(hi.x); v[5] = f2bf(hi.y); v[6] = f2bf(hi.z); v[7] = f2bf(hi.w);
      ((bf16x8*)xb)[id] = v;
    }
  } else {
    if (t < 8) {
      bf16x8 z = {0, 0, 0, 0, 0, 0, 0, 0};
      ((bf16x8*)(xb + (size_t)ZROW * 64))[t] = z;
    }
  }
}

// ---- build: ATOMICS ONLY (packed exch-chain + multi-flag) -------------------
__global__ __launch_bounds__(256) void build_kernel(const int* __restrict__ in_idx,
                                                    const int* __restrict__ out_idx,
                                                    u64* __restrict__ bh,
                                                    u64* __restrict__ node) {
  int id = blockIdx.x * 256 + threadIdx.x;
  if (id >= NPAIRS) return;
  int k  = id / M_PAIRS;
  int in = in_idx[id];
  int o  = out_idx[id];
  int bb = k * NPAD + o;
  u64 nh  = ((u64)(unsigned)in << 32) | (unsigned)id;
  u64 old = atomicExch(&bh[bb], nh);
  node[id] = old;
  // any non-first inserter flags multi; last exch-er always sees old!=SENT
  // and its OR lands after its own exch -> flag sticks on the final head.
  if (old != SENT) atomicOr(&bh[bb], MFLAG);
}

// ---- compact: pure coalesced head -> ginx; multi -> aux slot ----------------
__global__ __launch_bounds__(256) void compact_kernel(const u64* __restrict__ bh,
                                                      int* __restrict__ ginx,
                                                      u64* __restrict__ list,
                                                      int* __restrict__ ctrs) {
  __shared__ int l_cnt, l_base;
  int t = threadIdx.x;
  if (t == 0) l_cnt = 0;
  __syncthreads();
  int w = blockIdx.x * 256 + t;                 // 4 bins per thread
  bool ok = (w < NBINS / 4);
  u64 h[4];
  if (ok) {
    ulonglong2 p0 = ((const ulonglong2*)bh)[w * 2];
    ulonglong2 p1 = ((const ulonglong2*)bh)[w * 2 + 1];
    h[0] = p0.x; h[1] = p0.y; h[2] = p1.x; h[3] = p1.y;
  } else {
    h[0] = SENT; h[1] = SENT; h[2] = SENT; h[3] = SENT;
  }
  int gv[4], lp[4];
  #pragma unroll
  for (int s = 0; s < 4; ++s) {
    lp[s] = -1;
    if (h[s] == SENT)            gv[s] = ZROW;
    else if (!(h[s] >> 63))      gv[s] = (int)((h[s] >> 32) & 0x7FFFFFFFu);
    else                         lp[s] = atomicAdd(&l_cnt, 1);
  }
  __syncthreads();
  if (t == 0) l_base = (l_cnt > 0) ? atomicAdd(&ctrs[0], l_cnt) : 0;
  __syncthreads();
  #pragma unroll
  for (int s = 0; s < 4; ++s) {
    if (lp[s] >= 0) {
      int pos = l_base + lp[s];
      if (pos < AUXCAP) { list[pos] = h[s]; gv[s] = N_VOX + pos; }
      else              { gv[s] = (int)((h[s] >> 32) & 0x7FFFFFFFu); }  // guard
    }
  }
  if (ok) ((int4*)ginx)[w] = make_int4(gv[0], gv[1], gv[2], gv[3]);
}

// ---- fixup: aux row = f32 sum of chain's input rows (wave per bin) ----------
__global__ __launch_bounds__(256) void fixup_kernel(short* __restrict__ xb,
                                                    const u64* __restrict__ list,
                                                    const u64* __restrict__ node,
                                                    const int* __restrict__ ctrs) {
  int n = ctrs[0]; if (n > AUXCAP) n = AUXCAP;
  int wid  = (blockIdx.x * 256 + threadIdx.x) >> 6;
  int lane = threadIdx.x & 63;
  int nw   = gridDim.x * 4;
  for (int i = wid; i < n; i += nw) {
    u64 h = list[i];
    int in0     = (int)((h >> 32) & 0x7FFFFFFFu);
    unsigned id = (unsigned)(h & 0xFFFFFFFFu);
    float acc = bf2f(xb[(size_t)in0 * 64 + lane]);
    u64 v = node[id];                           // wave-uniform broadcast
    while (v != SENT) {
      int in = (int)((v >> 32) & 0x7FFFFFFFu);
      id = (unsigned)(v & 0xFFFFFFFFu);
      acc += bf2f(xb[(size_t)in * 64 + lane]);
      v = node[id];
    }
    xb[(size_t)(N_VOX + i) * 64 + lane] = f2bf(acc);
  }
}

// ---- conv: 128 rows/block (32/wave); DEPTH-2 row prefetch (3 stages in
//      flight), fully unrolled k-loop (static stage indices); W[k] LDS dbuf
//      + XOR-swizzle; fused BN stats; no launch-bounds cap -------------------
// A lane l: row=l&15, k-slots (l>>4)*8+j (+32);  B lane l: col=l&15, same slots.
// C/D: col=lane&15, row=(lane>>4)*4+reg  [rounds 1-9 proven].
// LDS swizzle: logical byte ^= ((row c)&7)<<4   [rounds 5-9 proven].
#define LOADST(S, ia, ib)                                       \
  { const short* _pa = xb + (size_t)(ia) * 64;                  \
    const short* _pb = xb + (size_t)(ib) * 64;                  \
    S[0] = *(const bf16x8*)(_pa + g8);                          \
    S[1] = *(const bf16x8*)(_pa + 32 + g8);                     \
    S[2] = *(const bf16x8*)(_pb + g8);                          \
    S[3] = *(const bf16x8*)(_pb + 32 + g8); }

__global__ __launch_bounds__(256) void conv_out_kernel(const short* __restrict__ xb,
                                                       const short* __restrict__ wt,
                                                       const int* __restrict__ ginx,
                                                       float* __restrict__ out,
                                                       float* __restrict__ stats) {
  __shared__ short lds[2 * 4096];               // 2 x 8 KB W double buffer
  __shared__ float ls[128];
  int t = threadIdx.x, wave = t >> 6, lane = t & 63;
  int g = lane >> 4, c0 = lane & 15, g8 = g * 8;
  int o0 = blockIdx.x * 128 + wave * 32 + c0;   // rows 0..15 of this wave
  int o1 = o0 + 16;                             // rows 16..31

  int rb  = ((c0 * 128 + g * 16) ^ ((c0 & 7) << 4)) >> 1;
  int wb0 = ((t * 32) ^ (((t >> 2) & 7) << 4)) >> 1;
  if (t < 128) ls[t] = 0.f;

  f32x4 acc0[4], acc1[4];
  #pragma unroll
  for (int n = 0; n < 4; ++n) {
    acc0[n][0]=0.f; acc0[n][1]=0.f; acc0[n][2]=0.f; acc0[n][3]=0.f;
    acc1[n][0]=0.f; acc1[n][1]=0.f; acc1[n][2]=0.f; acc1[n][3]=0.f;
  }

  // 3 gather stages; all st indices static after full unroll
  bf16x8 st[3][4];
  bf16x8 s0w = *(const bf16x8*)(wt + t * 16);
  bf16x8 s1w = *(const bf16x8*)(wt + t * 16 + 8);
  {
    int ia = ginx[o0], ib = ginx[o1];
    LOADST(st[0], ia, ib);                      // rows k=0
    ia = ginx[NPAD + o0]; ib = ginx[NPAD + o1];
    LOADST(st[1], ia, ib);                      // rows k=1
  }
  int i2a = ginx[2 * NPAD + o0], i2b = ginx[2 * NPAD + o1];   // idx k=2
  *(bf16x8*)&lds[wb0]     = s0w;
  *(bf16x8*)&lds[wb0 ^ 8] = s1w;
  __syncthreads();

  int buf = 0;
  #pragma unroll
  for (int k = 0; k < K3; ++k) {
    if (k + 1 < K3) {                           // W stage loads for k+1
      const short* wn = wt + (size_t)(k + 1) * 4096 + t * 16;
      s0w = *(const bf16x8*)(wn);
      s1w = *(const bf16x8*)(wn + 8);
    }
    if (k + 2 < K3) LOADST(st[(k + 2) % 3], i2a, i2b);   // rows k+2
    if (k + 3 < K3) {                           // idx k+3
      i2a = ginx[(size_t)(k + 3) * NPAD + o0];
      i2b = ginx[(size_t)(k + 3) * NPAD + o1];
    }
    // compute k from lds[buf] with stage st[k%3]
    const short* lb = lds + buf * 4096;
    #pragma unroll
    for (int n = 0; n < 4; ++n) {
      bf16x8 b0 = *(const bf16x8*)&lb[rb + n * 1024];
      bf16x8 b1 = *(const bf16x8*)&lb[(rb ^ 32) + n * 1024];
      acc0[n] = __builtin_amdgcn_mfma_f32_16x16x32_bf16(st[k % 3][0], b0, acc0[n], 0, 0, 0);
      acc0[n] = __builtin_amdgcn_mfma_f32_16x16x32_bf16(st[k % 3][1], b1, acc0[n], 0, 0, 0);
      acc1[n] = __builtin_amdgcn_mfma_f32_16x16x32_bf16(st[k % 3][2], b0, acc1[n], 0, 0, 0);
      acc1[n] = __builtin_amdgcn_mfma_f32_16x16x32_bf16(st[k % 3][3], b1, acc1[n], 0, 0, 0);
    }
    if (k + 1 < K3) {                           // publish W k+1
      short* wd = lds + (buf ^ 1) * 4096;
      *(bf16x8*)&wd[wb0]     = s0w;
      *(bf16x8*)&wd[wb0 ^ 8] = s1w;
    }
    __syncthreads();
    buf ^= 1;
  }

  // store: each out row exactly once
  int orow = blockIdx.x * 128 + wave * 32 + (g << 2);
  #pragma unroll
  for (int j = 0; j < 4; ++j) {
    int r0 = orow + j, r1 = orow + 16 + j;
    if (r0 < N_VOX) {
      float* op = out + (size_t)r0 * 64 + c0;
      op[0] = acc0[0][j]; op[16] = acc0[1][j]; op[32] = acc0[2][j]; op[48] = acc0[3][j];
    }
    if (r1 < N_VOX) {
      float* op = out + (size_t)r1 * 64 + c0;
      op[0] = acc1[0][j]; op[16] = acc1[1][j]; op[32] = acc1[2][j]; op[48] = acc1[3][j];
    }
  }

  // fused BN stats (padding rows hold exact zeros -> contribute nothing)
  #pragma unroll
  for (int n = 0; n < 4; ++n) {
    float s = 0.f, q = 0.f;
    #pragma unroll
    for (int j = 0; j < 4; ++j) {
      float v0 = acc0[n][j], v1 = acc1[n][j];
      s += v0 + v1; q += v0 * v0 + v1 * v1;
    }
    atomicAdd(&ls[n * 16 + c0], s);
    atomicAdd(&ls[64 + n * 16 + c0], q);
  }
  __syncthreads();
  if (t < 128) unsafeAtomicAdd(&stats[t], ls[t]);
}

// ---- finalize BN + ReLU in place -------------------------------------------
__global__ __launch_bounds__(256) void norm_kernel(float* __restrict__ out,
                                                   const float* __restrict__ stats,
                                                   const float* __restrict__ gamma,
                                                   const float* __restrict__ beta) {
  int i4 = blockIdx.x * 256 + threadIdx.x;
  if (i4 >= N_VOX * 16) return;
  const float invN = 1.0f / (float)N_VOX;
  float4 v = ((const float4*)out)[i4];
  int c0 = (i4 << 2) & 63;
  float r[4] = {v.x, v.y, v.z, v.w};
  #pragma unroll
  for (int j = 0; j < 4; ++j) {
    int c = c0 + j;
    float mean = stats[c] * invN;
    float ex2  = stats[64 + c] * invN;
    float var  = ex2 - mean * mean;
    float scale = gamma[c] * rsqrtf(var + BN_EPS);
    float shift = beta[c] - mean * scale;
    r[j] = fmaxf(r[j] * scale + shift, 0.0f);
  }
  v.x = r[0]; v.y = r[1]; v.z = r[2]; v.w = r[3];
  ((float4*)out)[i4] = v;
}

extern "C" void kernel_launch(void* const* d_in, const int* in_sizes, int n_in,
                              void* d_out, int out_size, void* d_ws, size_t ws_size,
                              hipStream_t stream) {
  const float* x      = (const float*)d_in[0];
  const float* W      = (const float*)d_in[1];
  const float* gamma  = (const float*)d_in[2];
  const float* beta   = (const float*)d_in[3];
  const int*   in_idx = (const int*)d_in[4];
  const int*   out_idx= (const int*)d_in[5];
  float* out = (float*)d_out;

  char* ws = (char*)d_ws;
  short* wt    = (short*)(ws + OFF_WT);
  float* stats = (float*)(ws + OFF_STATS);
  int*   ctrs  = (int*)(ws + OFF_CTRS);
  int*   ginx  = (int*)(ws + OFF_GINX);
  u64*   node  = (u64*)(ws + OFF_NODE);
  u64*   list  = (u64*)(ws + OFF_LIST);
  short* xb    = (short*)(ws + OFF_XB);
  u64*   bh    = (u64*)(ws + OFF_BH);           // aliased into xb aux region

  hipMemsetAsync(ws + OFF_STATS, 0, OFF_GINX - OFF_STATS, stream);  // stats+ctrs
  hipMemsetAsync((void*)bh, 0xFF, (size_t)NBINS * 8, stream);       // heads = SENT

  init_kernel<<<GRID_IN, 256, 0, stream>>>(W, x, wt, xb);
  build_kernel<<<NB_BUILD, 256, 0, stream>>>(in_idx, out_idx, bh, node);
  compact_kernel<<<(NBINS / 4 + 255) / 256, 256, 0, stream>>>(bh, ginx, list, ctrs);
  fixup_kernel<<<2048, 256, 0, stream>>>(xb, list, node, ctrs);
  conv_out_kernel<<<NPAD / 128, 256, 0, stream>>>(xb, wt, ginx, out, stats);
  norm_kernel<<<(N_VOX * 16 + 255) / 256, 256, 0, stream>>>(out, stats, gamma, beta);
}

// Round 11
// 213.761 us; speedup vs baseline: 1.1038x; 1.0204x over previous
//
#include <hip/hip_runtime.h>

// Sparse conv block, output-major, int32 exch-chain (round 11):
//   init (streaming only): bf16 prep of W/x, ZROW
//   build (atomics only): per pair int32 atomicExch head (10.8 MB table,
//          L2-resident) + coalesced int2 node write {prev, in}
//   compact: coalesced head read; non-empty -> 1 scattered node read:
//            single (prev<0) -> ginx=in ; multi -> aux slot
//   fixup: aux rows = f32 sum of chain rows (wave per bin)
//   conv: 128 rows/block, depth-2 row prefetch, W[k] LDS dbuf + XOR-swizzle,
//         fused BN stats
//   norm: BN+ReLU.                                MI355X / gfx950.

#define N_VOX   100000
#define NPAD    100096                  // multiple of 64
#define K3      27
#define M_PAIRS 40000
#define NPAIRS  (K3 * M_PAIRS)          // 1,080,000
#define BN_EPS  1e-5f
#define NBINS   (K3 * NPAD)             // 2,702,592
#define AUXMAX  184320                  // E[cnt>=2 bins] = 166.2k
#define AUXCAP  (AUXMAX - 1)
#define ZROW    (N_VOX + AUXMAX - 1)    // zeroed gather row (empty bins)

// ---- workspace layout (bytes), total 56,802,432 (< proven-fit 64,903,232) ---
#define OFF_WT     0u                       // bf16 Wt[k][c][i]        221,184
#define OFF_STATS  221184u                  // f32[128]
#define OFF_CTRS   221696u                  // [0]=aux counter
#define OFF_GINX   221760u                  // int ginx[NBINS]      10,810,368
#define OFF_NODE   11032128u                // int2 node[NPAIRS]     8,640,000
#define OFF_LIST   19672128u                // int list[AUXMAX]        737,280
#define OFF_XB     20409472u                // bf16 rows[N_VOX+AUXMAX][64]
// bh aliased into xb's AUX region: bh = aux rows [0, 84456); dead after
// compact (fixup overwrites allocated slots only afterwards); ZROW is aux row
// 184319 at byte 56,802,304 -- beyond bh end 44,019,840, no clash.
#define OFF_BH     (OFF_XB + 12800000u)     // int bh[NBINS]        10,810,368
#define WS_NEED    ((size_t)OFF_XB + (size_t)(N_VOX + AUXMAX) * 128u)

#define NB_WT    432                    // 27*4096/256
#define NB_XB    3125                   // ceil(N_VOX*8/256)
#define GRID_IN  (NB_WT + NB_XB + 1)    // 3558
#define NB_BUILD 4219                   // ceil(NPAIRS/256)

typedef __attribute__((ext_vector_type(8))) short bf16x8;
typedef __attribute__((ext_vector_type(4))) float f32x4;

__device__ __forceinline__ short f2bf(float f) {
  unsigned u = __builtin_bit_cast(unsigned, f);
  u += 0x7FFFu + ((u >> 16) & 1u);
  return (short)(u >> 16);
}
__device__ __forceinline__ float bf2f(short s) {
  unsigned u = ((unsigned)(unsigned short)s) << 16;
  return __builtin_bit_cast(float, u);
}

// ---- init: pure streaming ---------------------------------------------------
__global__ __launch_bounds__(256) void init_kernel(const float* __restrict__ W,
                                                   const float* __restrict__ x,
                                                   short* __restrict__ wt,
                                                   short* __restrict__ xb) {
  int b = blockIdx.x, t = threadIdx.x;
  if (b < NB_WT) {
    int id = b * 256 + t;
    int k = id >> 12, rem = id & 4095, c = rem >> 6, i = rem & 63;
    wt[id] = f2bf(W[(k << 12) + (i << 6) + c]);     // wt[k][c][i]
  } else if (b < NB_WT + NB_XB) {
    int id = (b - NB_WT) * 256 + t;
    if (id < N_VOX * 8) {
      float4 lo = ((const float4*)x)[id * 2];
      float4 hi = ((const float4*)x)[id * 2 + 1];
      bf16x8 v;
      v[0] = f2bf(lo.x); v[1] = f2bf(lo.y); v[2] = f2bf(lo.z); v[3] = f2bf(lo.w);
      v[4] = f2bf(hi.x); v[5] = f2bf(hi.y); v[6] = f2bf(hi.z); v[7] = f2bf(hi.w);
      ((bf16x8*)xb)[id] = v;
    }
  } else {
    if (t < 8) {
      bf16x8 z = {0, 0, 0, 0, 0, 0, 0, 0};
      ((bf16x8*)(xb + (size_t)ZROW * 64))[t] = z;
    }
  }
}

// ---- build: atomics only, int32 heads (L2-resident 10.8 MB table) -----------
__global__ __launch_bounds__(256) void build_kernel(const int* __restrict__ in_idx,
                                                    const int* __restrict__ out_idx,
                                                    int* __restrict__ bh,
                                                    int2* __restrict__ node) {
  int id = blockIdx.x * 256 + threadIdx.x;
  if (id >= NPAIRS) return;
  int k  = id / M_PAIRS;
  int in = in_idx[id];
  int o  = out_idx[id];
  int bb = k * NPAD + o;
  int old = atomicExch(&bh[bb], id);
  node[id] = make_int2(old, in);                // {prev, in}, coalesced
}

// ---- compact: coalesced head read; 1 scattered node read per non-empty bin --
__global__ __launch_bounds__(256) void compact_kernel(const int* __restrict__ bh,
                                                      const int2* __restrict__ node,
                                                      int* __restrict__ ginx,
                                                      int* __restrict__ list,
                                                      int* __restrict__ ctrs) {
  __shared__ int l_cnt, l_base;
  int t = threadIdx.x;
  if (t == 0) l_cnt = 0;
  __syncthreads();
  int w = blockIdx.x * 256 + t;                 // 4 bins per thread
  bool ok = (w < NBINS / 4);
  int4 h4 = ok ? ((const int4*)bh)[w] : make_int4(-1, -1, -1, -1);
  int hv[4] = {h4.x, h4.y, h4.z, h4.w};
  int gv[4], lp[4];
  int2 n0[4];
  #pragma unroll
  for (int s = 0; s < 4; ++s) {
    lp[s] = -1;
    if (hv[s] < 0) gv[s] = ZROW;
    else {
      n0[s] = node[hv[s]];                      // scattered int2 (L3-fed)
      if (n0[s].x < 0) gv[s] = n0[s].y;         // single input
      else             lp[s] = atomicAdd(&l_cnt, 1);
    }
  }
  __syncthreads();
  if (t == 0) l_base = (l_cnt > 0) ? atomicAdd(&ctrs[0], l_cnt) : 0;
  __syncthreads();
  #pragma unroll
  for (int s = 0; s < 4; ++s) {
    if (lp[s] >= 0) {
      int pos = l_base + lp[s];
      if (pos < AUXCAP) { list[pos] = hv[s]; gv[s] = N_VOX + pos; }
      else              { gv[s] = n0[s].y; }    // overflow guard (won't hit)
    }
  }
  if (ok) ((int4*)ginx)[w] = make_int4(gv[0], gv[1], gv[2], gv[3]);
}

// ---- fixup: aux row = f32 sum of chain's input rows (wave per bin) ----------
__global__ __launch_bounds__(256) void fixup_kernel(short* __restrict__ xb,
                                                    const int* __restrict__ list,
                                                    const int2* __restrict__ node,
                                                    const int* __restrict__ ctrs) {
  int n = ctrs[0]; if (n > AUXCAP) n = AUXCAP;
  int wid  = (blockIdx.x * 256 + threadIdx.x) >> 6;
  int lane = threadIdx.x & 63;
  int nw   = gridDim.x * 4;
  for (int i = wid; i < n; i += nw) {
    int h = list[i];
    float acc = 0.f;
    while (h >= 0) {
      int2 nd = node[h];                        // wave-uniform broadcast
      acc += bf2f(xb[(size_t)nd.y * 64 + lane]);
      h = nd.x;
    }
    xb[(size_t)(N_VOX + i) * 64 + lane] = f2bf(acc);
  }
}

// ---- conv: 128 rows/block (32/wave); depth-2 row prefetch (3 stages),
//      fully unrolled k-loop; W[k] LDS dbuf + XOR-swizzle; fused BN stats ----
// A lane l: row=l&15, k-slots (l>>4)*8+j (+32);  B lane l: col=l&15, same slots.
// C/D: col=lane&15, row=(lane>>4)*4+reg  [rounds 1-10 proven].
// LDS swizzle: logical byte ^= ((row c)&7)<<4   [rounds 5-10 proven].
#define LOADST(S, ia, ib)                                       \
  { const short* _pa = xb + (size_t)(ia) * 64;                  \
    const short* _pb = xb + (size_t)(ib) * 64;                  \
    S[0] = *(const bf16x8*)(_pa + g8);                          \
    S[1] = *(const bf16x8*)(_pa + 32 + g8);                     \
    S[2] = *(const bf16x8*)(_pb + g8);                          \
    S[3] = *(const bf16x8*)(_pb + 32 + g8); }

__global__ __launch_bounds__(256) void conv_out_kernel(const short* __restrict__ xb,
                                                       const short* __restrict__ wt,
                                                       const int* __restrict__ ginx,
                                                       float* __restrict__ out,
                                                       float* __restrict__ stats) {
  __shared__ short lds[2 * 4096];               // 2 x 8 KB W double buffer
  __shared__ float ls[128];
  int t = threadIdx.x, wave = t >> 6, lane = t & 63;
  int g = lane >> 4, c0 = lane & 15, g8 = g * 8;
  int o0 = blockIdx.x * 128 + wave * 32 + c0;   // rows 0..15 of this wave
  int o1 = o0 + 16;                             // rows 16..31

  int rb  = ((c0 * 128 + g * 16) ^ ((c0 & 7) << 4)) >> 1;
  int wb0 = ((t * 32) ^ (((t >> 2) & 7) << 4)) >> 1;
  if (t < 128) ls[t] = 0.f;

  f32x4 acc0[4], acc1[4];
  #pragma unroll
  for (int n = 0; n < 4; ++n) {
    acc0[n][0]=0.f; acc0[n][1]=0.f; acc0[n][2]=0.f; acc0[n][3]=0.f;
    acc1[n][0]=0.f; acc1[n][1]=0.f; acc1[n][2]=0.f; acc1[n][3]=0.f;
  }

  // 3 gather stages; all st indices static after full unroll
  bf16x8 st[3][4];
  bf16x8 s0w = *(const bf16x8*)(wt + t * 16);
  bf16x8 s1w = *(const bf16x8*)(wt + t * 16 + 8);
  {
    int ia = ginx[o0], ib = ginx[o1];
    LOADST(st[0], ia, ib);                      // rows k=0
    ia = ginx[NPAD + o0]; ib = ginx[NPAD + o1];
    LOADST(st[1], ia, ib);                      // rows k=1
  }
  int i2a = ginx[2 * NPAD + o0], i2b = ginx[2 * NPAD + o1];   // idx k=2
  *(bf16x8*)&lds[wb0]     = s0w;
  *(bf16x8*)&lds[wb0 ^ 8] = s1w;
  __syncthreads();

  int buf = 0;
  #pragma unroll
  for (int k = 0; k < K3; ++k) {
    if (k + 1 < K3) {                           // W stage loads for k+1
      const short* wn = wt + (size_t)(k + 1) * 4096 + t * 16;
      s0w = *(const bf16x8*)(wn);
      s1w = *(const bf16x8*)(wn + 8);
    }
    if (k + 2 < K3) LOADST(st[(k + 2) % 3], i2a, i2b);   // rows k+2
    if (k + 3 < K3) {                           // idx k+3
      i2a = ginx[(size_t)(k + 3) * NPAD + o0];
      i2b = ginx[(size_t)(k + 3) * NPAD + o1];
    }
    // compute k from lds[buf] with stage st[k%3]
    const short* lb = lds + buf * 4096;
    #pragma unroll
    for (int n = 0; n < 4; ++n) {
      bf16x8 b0 = *(const bf16x8*)&lb[rb + n * 1024];
      bf16x8 b1 = *(const bf16x8*)&lb[(rb ^ 32) + n * 1024];
      acc0[n] = __builtin_amdgcn_mfma_f32_16x16x32_bf16(st[k % 3][0], b0, acc0[n], 0, 0, 0);
      acc0[n] = __builtin_amdgcn_mfma_f32_16x16x32_bf16(st[k % 3][1], b1, acc0[n], 0, 0, 0);
      acc1[n] = __builtin_amdgcn_mfma_f32_16x16x32_bf16(st[k % 3][2], b0, acc1[n], 0, 0, 0);
      acc1[n] = __builtin_amdgcn_mfma_f32_16x16x32_bf16(st[k % 3][3], b1, acc1[n], 0, 0, 0);
    }
    if (k + 1 < K3) {                           // publish W k+1
      short* wd = lds + (buf ^ 1) * 4096;
      *(bf16x8*)&wd[wb0]     = s0w;
      *(bf16x8*)&wd[wb0 ^ 8] = s1w;
    }
    __syncthreads();
    buf ^= 1;
  }

  // store: each out row exactly once
  int orow = blockIdx.x * 128 + wave * 32 + (g << 2);
  #pragma unroll
  for (int j = 0; j < 4; ++j) {
    int r0 = orow + j, r1 = orow + 16 + j;
    if (r0 < N_VOX) {
      float* op = out + (size_t)r0 * 64 + c0;
      op[0] = acc0[0][j]; op[16] = acc0[1][j]; op[32] = acc0[2][j]; op[48] = acc0[3][j];
    }
    if (r1 < N_VOX) {
      float* op = out + (size_t)r1 * 64 + c0;
      op[0] = acc1[0][j]; op[16] = acc1[1][j]; op[32] = acc1[2][j]; op[48] = acc1[3][j];
    }
  }

  // fused BN stats (padding rows hold exact zeros -> contribute nothing)
  #pragma unroll
  for (int n = 0; n < 4; ++n) {
    float s = 0.f, q = 0.f;
    #pragma unroll
    for (int j = 0; j < 4; ++j) {
      float v0 = acc0[n][j], v1 = acc1[n][j];
      s += v0 + v1; q += v0 * v0 + v1 * v1;
    }
    atomicAdd(&ls[n * 16 + c0], s);
    atomicAdd(&ls[64 + n * 16 + c0], q);
  }
  __syncthreads();
  if (t < 128) unsafeAtomicAdd(&stats[t], ls[t]);
}

// ---- finalize BN + ReLU in place -------------------------------------------
__global__ __launch_bounds__(256) void norm_kernel(float* __restrict__ out,
                                                   const float* __restrict__ stats,
                                                   const float* __restrict__ gamma,
                                                   const float* __restrict__ beta) {
  int i4 = blockIdx.x * 256 + threadIdx.x;
  if (i4 >= N_VOX * 16) return;
  const float invN = 1.0f / (float)N_VOX;
  float4 v = ((const float4*)out)[i4];
  int c0 = (i4 << 2) & 63;
  float r[4] = {v.x, v.y, v.z, v.w};
  #pragma unroll
  for (int j = 0; j < 4; ++j) {
    int c = c0 + j;
    float mean = stats[c] * invN;
    float ex2  = stats[64 + c] * invN;
    float var  = ex2 - mean * mean;
    float scale = gamma[c] * rsqrtf(var + BN_EPS);
    float shift = beta[c] - mean * scale;
    r[j] = fmaxf(r[j] * scale + shift, 0.0f);
  }
  v.x = r[0]; v.y = r[1]; v.z = r[2]; v.w = r[3];
  ((float4*)out)[i4] = v;
}

extern "C" void kernel_launch(void* const* d_in, const int* in_sizes, int n_in,
                              void* d_out, int out_size, void* d_ws, size_t ws_size,
                              hipStream_t stream) {
  const float* x      = (const float*)d_in[0];
  const float* W      = (const float*)d_in[1];
  const float* gamma  = (const float*)d_in[2];
  const float* beta   = (const float*)d_in[3];
  const int*   in_idx = (const int*)d_in[4];
  const int*   out_idx= (const int*)d_in[5];
  float* out = (float*)d_out;

  char* ws = (char*)d_ws;
  short* wt    = (short*)(ws + OFF_WT);
  float* stats = (float*)(ws + OFF_STATS);
  int*   ctrs  = (int*)(ws + OFF_CTRS);
  int*   ginx  = (int*)(ws + OFF_GINX);
  int2*  node  = (int2*)(ws + OFF_NODE);
  int*   list  = (int*)(ws + OFF_LIST);
  short* xb    = (short*)(ws + OFF_XB);
  int*   bh    = (int*)(ws + OFF_BH);           // aliased into xb aux region

  hipMemsetAsync(ws + OFF_STATS, 0, OFF_GINX - OFF_STATS, stream);  // stats+ctrs
  hipMemsetAsync((void*)bh, 0xFF, (size_t)NBINS * 4, stream);       // heads = -1

  init_kernel<<<GRID_IN, 256, 0, stream>>>(W, x, wt, xb);
  build_kernel<<<NB_BUILD, 256, 0, stream>>>(in_idx, out_idx, bh, node);
  compact_kernel<<<(NBINS / 4 + 255) / 256, 256, 0, stream>>>(bh, node, ginx, list, ctrs);
  fixup_kernel<<<2048, 256, 0, stream>>>(xb, list, node, ctrs);
  conv_out_kernel<<<NPAD / 128, 256, 0, stream>>>(xb, wt, ginx, out, stats);
  norm_kernel<<<(N_VOX * 16 + 255) / 256, 256, 0, stream>>>(out, stats, gamma, beta);
}